// Round 1
// baseline (9598.431 us; speedup 1.0000x reference)
//
#include <hip/hip_runtime.h>
#include <cstdint>
#include <cstddef>

// Problem constants (GRUEncoder: B=64, T=4096, D=128, H=256, C=128)
#define B_  64
#define T_  4096
#define D_  128
#define H_  256
#define C_  128
#define G3  768   // 3*H

typedef _Float16 half2v __attribute__((ext_vector_type(2)));
typedef _Float16 half8v __attribute__((ext_vector_type(8)));
typedef short    short8v __attribute__((ext_vector_type(8)));
typedef float    float4v __attribute__((ext_vector_type(4)));

static __device__ __forceinline__ float dot2f(half2v a, half2v b, float c) {
#if __has_builtin(__builtin_amdgcn_fdot2)
  return __builtin_amdgcn_fdot2(a, b, c, false);   // v_dot2_f32_f16: 2 MAC/lane/cyc
#else
  return c + (float)a[0] * (float)b[0] + (float)a[1] * (float)b[1];
#endif
}

static __device__ __forceinline__ float fast_rcp(float x) {
#if __has_builtin(__builtin_amdgcn_rcpf)
  return __builtin_amdgcn_rcpf(x);
#else
  return 1.0f / x;
#endif
}

// float -> bf16 (round to nearest even), finite inputs only
static __device__ __forceinline__ short f2bf(float f) {
  union { float f; unsigned u; } v; v.f = f;
  unsigned r = (v.u + 0x7FFFu + ((v.u >> 16) & 1u)) >> 16;
  return (short)r;
}

// ---------------------------------------------------------------------------
// Kernel 1: igates[m][n] = sum_k x[m][k] * w_ih[n][k],  m = b*T+t (262144), n in [0,768), k in [0,128)
// Output fp16 to workspace. bf16 MFMA 16x16x32; block = 4 waves; wave handles 64 m-rows x all 768 n.
// Fragment layouts (HW-verified, learn_hip m89/m120):
//   A[m][k]: m = lane&15, k = (lane>>4)*8 + i      (8 halves / 4 VGPRs)
//   B[k][n]: n = lane&15, k = (lane>>4)*8 + i
//   C[row][col]: col = lane&15, row = (lane>>4)*4 + i
// ---------------------------------------------------------------------------
__global__ __launch_bounds__(256) void igates_gemm(const float* __restrict__ x,
                                                   const float* __restrict__ w_ih,
                                                   _Float16* __restrict__ igs) {
  const int lane = threadIdx.x & 63;
  const int wave = threadIdx.x >> 6;
  const int r = lane & 15;
  const int g = lane >> 4;
  const int m_base = blockIdx.x * 256 + wave * 64;

  // Load + convert A fragments for 4 m-tiles x 4 k-frags (x read exactly once)
  short8v a[4][4];
#pragma unroll
  for (int mi = 0; mi < 4; ++mi) {
    const float* xr = x + (size_t)(m_base + mi * 16 + r) * D_;
#pragma unroll
    for (int kf = 0; kf < 4; ++kf) {
      const float4v u = *(const float4v*)(xr + kf * 32 + g * 8);
      const float4v v = *(const float4v*)(xr + kf * 32 + g * 8 + 4);
      short8v t;
      t[0] = f2bf(u[0]); t[1] = f2bf(u[1]); t[2] = f2bf(u[2]); t[3] = f2bf(u[3]);
      t[4] = f2bf(v[0]); t[5] = f2bf(v[1]); t[6] = f2bf(v[2]); t[7] = f2bf(v[3]);
      a[mi][kf] = t;
    }
  }

  for (int nt = 0; nt < 48; ++nt) {
    const float* wr = w_ih + (size_t)(nt * 16 + r) * D_;
    short8v bf[4];
#pragma unroll
    for (int kf = 0; kf < 4; ++kf) {
      const float4v u = *(const float4v*)(wr + kf * 32 + g * 8);
      const float4v v = *(const float4v*)(wr + kf * 32 + g * 8 + 4);
      short8v t;
      t[0] = f2bf(u[0]); t[1] = f2bf(u[1]); t[2] = f2bf(u[2]); t[3] = f2bf(u[3]);
      t[4] = f2bf(v[0]); t[5] = f2bf(v[1]); t[6] = f2bf(v[2]); t[7] = f2bf(v[3]);
      bf[kf] = t;
    }
    float4v acc[4];
#pragma unroll
    for (int mi = 0; mi < 4; ++mi) { acc[mi][0] = 0.f; acc[mi][1] = 0.f; acc[mi][2] = 0.f; acc[mi][3] = 0.f; }
#pragma unroll
    for (int kf = 0; kf < 4; ++kf)
#pragma unroll
      for (int mi = 0; mi < 4; ++mi)
        acc[mi] = __builtin_amdgcn_mfma_f32_16x16x32_bf16(a[mi][kf], bf[kf], acc[mi], 0, 0, 0);

    const int col = nt * 16 + r;
#pragma unroll
    for (int mi = 0; mi < 4; ++mi) {
      const int rowb = m_base + mi * 16 + g * 4;
#pragma unroll
      for (int i = 0; i < 4; ++i)
        igs[(size_t)(rowb + i) * G3 + col] = (_Float16)acc[mi][i];
    }
  }
}

// ---------------------------------------------------------------------------
// Kernel 2: sequential GRU scan. One workgroup per batch element (64 wgs).
// 256 threads; thread j owns hidden column j: holds w_hh rows {j, 256+j, 512+j}
// as 3x128 half2 IN REGISTERS (384 VGPRs -> __launch_bounds__(256,1), 1 wave/SIMD).
// Per step: read h (fp16, LDS broadcast, 32x ds_read_b128), 384 v_dot2, gates,
// write own h_new to the other LDS buffer, ONE barrier. h kept fp32 in-register.
// ---------------------------------------------------------------------------
__global__ __launch_bounds__(256, 1) void gru_scan(const float* __restrict__ w_hh,
                                                   const float* __restrict__ bias,
                                                   const float* __restrict__ bn,
                                                   const float* __restrict__ w_proj,
                                                   const float* __restrict__ b_proj,
                                                   const _Float16* __restrict__ igs,
                                                   float* __restrict__ out) {
  const int j = threadIdx.x;
  const int bidx = blockIdx.x;

  __shared__ __align__(16) _Float16 hbuf[2][H_];
  __shared__ float hf[H_];

  // --- load this thread's weight rows into registers (fully unrolled => reg-promoted)
  half2v Wr[128], Wz[128], Wn[128];
  {
    const float4v* pr = (const float4v*)(w_hh + (size_t)j * H_);
    const float4v* pz = (const float4v*)(w_hh + (size_t)(H_ + j) * H_);
    const float4v* pn = (const float4v*)(w_hh + (size_t)(2 * H_ + j) * H_);
#pragma unroll
    for (int p = 0; p < 64; ++p) {
      float4v v;
      v = pr[p]; Wr[2 * p] = half2v{(_Float16)v[0], (_Float16)v[1]}; Wr[2 * p + 1] = half2v{(_Float16)v[2], (_Float16)v[3]};
      v = pz[p]; Wz[2 * p] = half2v{(_Float16)v[0], (_Float16)v[1]}; Wz[2 * p + 1] = half2v{(_Float16)v[2], (_Float16)v[3]};
      v = pn[p]; Wn[2 * p] = half2v{(_Float16)v[0], (_Float16)v[1]}; Wn[2 * p + 1] = half2v{(_Float16)v[2], (_Float16)v[3]};
    }
  }

  const float br  = bias[j];
  const float bz  = bias[H_ + j];
  const float bnb = bias[2 * H_ + j];
  const float bnj = bn[j];

  const _Float16* igbase = igs + (size_t)bidx * T_ * G3 + j;

  float h = 0.0f;
  hbuf[0][j] = (_Float16)0.0f;
  // igates for t=0 (current)
  float igr = (float)igbase[0];
  float igz = (float)igbase[H_];
  float ign = (float)igbase[2 * H_];
  __syncthreads();

  for (int t = 0; t < T_; ++t) {
    // prefetch igates for t+1 (~900cyc HBM latency hidden behind the dots)
    const int tn = (t + 1 < T_) ? (t + 1) : t;
    const _Float16* pnx = igbase + (size_t)tn * G3;
    const _Float16 nr = pnx[0];
    const _Float16 nz = pnx[H_];
    const _Float16 nn = pnx[2 * H_];

    float ar = 0.f, az = 0.f, an = 0.f;
    const half8v* hp = (const half8v*)(&hbuf[t & 1][0]);
#pragma unroll
    for (int p = 0; p < 32; ++p) {
      union { half8v v; half2v h2[4]; } u;
      u.v = hp[p];  // ds_read_b128, wave-uniform address -> broadcast (bank-free)
#pragma unroll
      for (int q = 0; q < 4; ++q) {
        ar = dot2f(u.h2[q], Wr[4 * p + q], ar);
        az = dot2f(u.h2[q], Wz[4 * p + q], az);
        an = dot2f(u.h2[q], Wn[4 * p + q], an);
      }
    }

    const float rv = fast_rcp(1.0f + __expf(-(igr + br + ar)));
    const float zv = fast_rcp(1.0f + __expf(-(igz + bz + az)));
    float npre = ign + bnb + rv * (an + bnj);
    npre = fminf(fmaxf(npre, -9.0f), 9.0f);      // avoid inf/inf NaN in tanh form
    const float e = __expf(-2.0f * npre);
    const float nv = (1.0f - e) * fast_rcp(1.0f + e);

    h = nv + zv * (h - nv);
    hbuf[(t & 1) ^ 1][j] = (_Float16)h;

    igr = (float)nr; igz = (float)nz; ign = (float)nn;
    __syncthreads();   // single barrier/step: double-buffered h
  }

  // --- epilogue: out[b] = h @ w_proj.T + b_proj  (fp32)
  hf[j] = h;
  __syncthreads();
  if (j < C_) {
    float acc = b_proj[j];
    const float4v* wp = (const float4v*)(w_proj + (size_t)j * H_);
#pragma unroll
    for (int p = 0; p < 64; ++p) {
      const float4v v = wp[p];
      acc += v[0] * hf[4 * p] + v[1] * hf[4 * p + 1] + v[2] * hf[4 * p + 2] + v[3] * hf[4 * p + 3];
    }
    out[bidx * C_ + j] = acc;
  }
}

// ---------------------------------------------------------------------------
// Inputs (fp32): 0:x_seq[B,T,D] 1:w_ih[768,128] 2:w_hh[768,256] 3:b[768]
//                4:bn[256] 5:w_proj[128,256] 6:b_proj[128]
// Output: fp32 [B,C] = 8192 elems.
// Workspace: igates fp16 [B*T, 768] = 402,653,184 bytes.
// ---------------------------------------------------------------------------
extern "C" void kernel_launch(void* const* d_in, const int* in_sizes, int n_in,
                              void* d_out, int out_size, void* d_ws, size_t ws_size,
                              hipStream_t stream) {
  const float* x      = (const float*)d_in[0];
  const float* w_ih   = (const float*)d_in[1];
  const float* w_hh   = (const float*)d_in[2];
  const float* bias   = (const float*)d_in[3];
  const float* bn     = (const float*)d_in[4];
  const float* w_proj = (const float*)d_in[5];
  const float* b_proj = (const float*)d_in[6];
  float* out = (float*)d_out;
  _Float16* igs = (_Float16*)d_ws;   // needs 384 MiB

  igates_gemm<<<dim3((B_ * T_) / 256), dim3(256), 0, stream>>>(x, w_ih, igs);
  gru_scan<<<dim3(B_), dim3(256), 0, stream>>>(w_hh, bias, bn, w_proj, b_proj, igs, out);
}

// Round 3
// 5031.803 us; speedup vs baseline: 1.9076x; 1.9076x over previous
//
#include <hip/hip_runtime.h>
#include <cstdint>
#include <cstddef>

// Problem constants (GRUEncoder: B=64, T=4096, D=128, H=256, C=128)
#define B_  64
#define T_  4096
#define D_  128
#define H_  256
#define C_  128
#define G3  768   // 3*H

typedef _Float16 half2v __attribute__((ext_vector_type(2)));
typedef _Float16 half8v __attribute__((ext_vector_type(8)));
typedef short    short8v __attribute__((ext_vector_type(8)));
typedef float    float4v __attribute__((ext_vector_type(4)));

static __device__ __forceinline__ float dot2f(half2v a, half2v b, float c) {
#if __has_builtin(__builtin_amdgcn_fdot2)
  return __builtin_amdgcn_fdot2(a, b, c, false);   // v_dot2_f32_f16: 2 MAC/lane/cyc
#else
  return c + (float)a[0] * (float)b[0] + (float)a[1] * (float)b[1];
#endif
}

static __device__ __forceinline__ float fast_rcp(float x) {
#if __has_builtin(__builtin_amdgcn_rcpf)
  return __builtin_amdgcn_rcpf(x);
#else
  return 1.0f / x;
#endif
}

// float -> bf16 (round to nearest even), finite inputs only
static __device__ __forceinline__ short f2bf(float f) {
  union { float f; unsigned u; } v; v.f = f;
  unsigned r = (v.u + 0x7FFFu + ((v.u >> 16) & 1u)) >> 16;
  return (short)r;
}

// ---------------------------------------------------------------------------
// Kernel 1: igates[m][n] = sum_k x[m][k] * w_ih[n][k]
// m = b*T+t (262144 rows), n in [0,768), k in [0,128). Output fp16 to ws.
// bf16 MFMA 16x16x32; block = 4 waves; wave handles 64 m-rows x all 768 n.
// Fragment layouts (HW-verified, learn_hip m89/m120):
//   A[m][k]: m = lane&15, k = (lane>>4)*8 + i
//   B[k][n]: n = lane&15, k = (lane>>4)*8 + i
//   C[row][col]: col = lane&15, row = (lane>>4)*4 + i
// ---------------------------------------------------------------------------
__global__ __launch_bounds__(256) void igates_gemm(const float* __restrict__ x,
                                                   const float* __restrict__ w_ih,
                                                   _Float16* __restrict__ igs) {
  const int lane = threadIdx.x & 63;
  const int wave = threadIdx.x >> 6;
  const int r = lane & 15;
  const int g = lane >> 4;
  const int m_base = blockIdx.x * 256 + wave * 64;

  short8v a[4][4];
#pragma unroll
  for (int mi = 0; mi < 4; ++mi) {
    const float* xr = x + (size_t)(m_base + mi * 16 + r) * D_;
#pragma unroll
    for (int kf = 0; kf < 4; ++kf) {
      const float4v u = *(const float4v*)(xr + kf * 32 + g * 8);
      const float4v v = *(const float4v*)(xr + kf * 32 + g * 8 + 4);
      short8v t;
      t[0] = f2bf(u[0]); t[1] = f2bf(u[1]); t[2] = f2bf(u[2]); t[3] = f2bf(u[3]);
      t[4] = f2bf(v[0]); t[5] = f2bf(v[1]); t[6] = f2bf(v[2]); t[7] = f2bf(v[3]);
      a[mi][kf] = t;
    }
  }

  for (int nt = 0; nt < 48; ++nt) {
    const float* wr = w_ih + (size_t)(nt * 16 + r) * D_;
    short8v bf[4];
#pragma unroll
    for (int kf = 0; kf < 4; ++kf) {
      const float4v u = *(const float4v*)(wr + kf * 32 + g * 8);
      const float4v v = *(const float4v*)(wr + kf * 32 + g * 8 + 4);
      short8v t;
      t[0] = f2bf(u[0]); t[1] = f2bf(u[1]); t[2] = f2bf(u[2]); t[3] = f2bf(u[3]);
      t[4] = f2bf(v[0]); t[5] = f2bf(v[1]); t[6] = f2bf(v[2]); t[7] = f2bf(v[3]);
      bf[kf] = t;
    }
    float4v acc[4];
#pragma unroll
    for (int mi = 0; mi < 4; ++mi) { acc[mi][0] = 0.f; acc[mi][1] = 0.f; acc[mi][2] = 0.f; acc[mi][3] = 0.f; }
#pragma unroll
    for (int kf = 0; kf < 4; ++kf)
#pragma unroll
      for (int mi = 0; mi < 4; ++mi)
        acc[mi] = __builtin_amdgcn_mfma_f32_16x16x32_bf16(a[mi][kf], bf[kf], acc[mi], 0, 0, 0);

    const int col = nt * 16 + r;
#pragma unroll
    for (int mi = 0; mi < 4; ++mi) {
      const int rowb = m_base + mi * 16 + g * 4;
#pragma unroll
      for (int i = 0; i < 4; ++i)
        igs[(size_t)(rowb + i) * G3 + col] = (_Float16)acc[mi][i];
    }
  }
}

// ---------------------------------------------------------------------------
// Kernel 2: sequential GRU scan. One workgroup per batch element (64 wgs).
// 512 threads; thread (j = tid&255, s = tid>>8) owns hidden column j, k-half s:
// holds w_hh[{j,256+j,512+j}][128s:128s+128] as 3 x 16 half8 = 192 VGPRs.
// __launch_bounds__(512,2) -> 256 VGPR budget, ~215 needed -> resident (fix for
// R0's spill: VGPR_Count was 204 + scratch, L2-reload-bound at 9.2 ms).
// Per step: LDS-broadcast h half (16 ds_read_b128), 192 v_dot2, write 3 fp32
// partials to LDS, barrier, low 256 threads combine + gate math + write h,
// barrier. h kept fp32 in-register by the gate threads.
// ---------------------------------------------------------------------------
__global__ __launch_bounds__(512, 2) void gru_scan(const float* __restrict__ w_hh,
                                                   const float* __restrict__ bias,
                                                   const float* __restrict__ bn,
                                                   const float* __restrict__ w_proj,
                                                   const float* __restrict__ b_proj,
                                                   const _Float16* __restrict__ igs,
                                                   float* __restrict__ out) {
  const int tid = threadIdx.x;
  const int j = tid & 255;
  const int s = tid >> 8;          // k-half: s=0 -> h[0:128), s=1 -> h[128:256)
  const int bidx = blockIdx.x;

  __shared__ __align__(16) _Float16 hbuf[H_];
  __shared__ float pbuf[3][2][H_];   // [gate][k-half][column]
  __shared__ float hf[H_];

  // --- weights for this thread: 48 half8 values (16-elt arrays => SROA-promoted)
  half8v Wr[16], Wz[16], Wn[16];
  {
    const float* p0 = w_hh + (size_t)j * H_ + 128 * s;
    const float* p1 = w_hh + (size_t)(H_ + j) * H_ + 128 * s;
    const float* p2 = w_hh + (size_t)(2 * H_ + j) * H_ + 128 * s;
#pragma unroll
    for (int i = 0; i < 16; ++i) {
      float4v u, v; half8v t;
      u = *(const float4v*)(p0 + 8 * i); v = *(const float4v*)(p0 + 8 * i + 4);
      t[0] = (_Float16)u[0]; t[1] = (_Float16)u[1]; t[2] = (_Float16)u[2]; t[3] = (_Float16)u[3];
      t[4] = (_Float16)v[0]; t[5] = (_Float16)v[1]; t[6] = (_Float16)v[2]; t[7] = (_Float16)v[3];
      Wr[i] = t;
      u = *(const float4v*)(p1 + 8 * i); v = *(const float4v*)(p1 + 8 * i + 4);
      t[0] = (_Float16)u[0]; t[1] = (_Float16)u[1]; t[2] = (_Float16)u[2]; t[3] = (_Float16)u[3];
      t[4] = (_Float16)v[0]; t[5] = (_Float16)v[1]; t[6] = (_Float16)v[2]; t[7] = (_Float16)v[3];
      Wz[i] = t;
      u = *(const float4v*)(p2 + 8 * i); v = *(const float4v*)(p2 + 8 * i + 4);
      t[0] = (_Float16)u[0]; t[1] = (_Float16)u[1]; t[2] = (_Float16)u[2]; t[3] = (_Float16)u[3];
      t[4] = (_Float16)v[0]; t[5] = (_Float16)v[1]; t[6] = (_Float16)v[2]; t[7] = (_Float16)v[3];
      Wn[i] = t;
    }
  }

  // --- gate-thread state (s==0 waves only; wave-uniform branch)
  float br = 0.f, bz = 0.f, bnb = 0.f, bnj = 0.f, h = 0.f;
  float igr = 0.f, igz = 0.f, ign = 0.f;
  const _Float16* igbase = igs + (size_t)bidx * T_ * G3 + j;
  if (s == 0) {
    br  = bias[j];
    bz  = bias[H_ + j];
    bnb = bias[2 * H_ + j];
    bnj = bn[j];
    igr = (float)igbase[0];
    igz = (float)igbase[H_];
    ign = (float)igbase[2 * H_];
    hbuf[j] = (_Float16)0.0f;
  }
  __syncthreads();

  for (int t = 0; t < T_; ++t) {
    // prefetch next step's igates early (covered by the dot loop below)
    _Float16 nr = (_Float16)0.f, nz = (_Float16)0.f, nn = (_Float16)0.f;
    if (s == 0) {
      const int tn = (t + 1 < T_) ? (t + 1) : t;
      const _Float16* pnx = igbase + (size_t)tn * G3;
      nr = pnx[0]; nz = pnx[H_]; nn = pnx[2 * H_];
    }

    // partial dots over this thread's k-half (h read is wave-uniform -> broadcast)
    float ar = 0.f, az = 0.f, an = 0.f;
    const half8v* hp = (const half8v*)(&hbuf[128 * s]);
#pragma unroll
    for (int i = 0; i < 16; ++i) {
      union { half8v v; half2v h2[4]; } uh, ur, uz, un;
      uh.v = hp[i];   // ds_read_b128 broadcast
      ur.v = Wr[i]; uz.v = Wz[i]; un.v = Wn[i];
#pragma unroll
      for (int q = 0; q < 4; ++q) {
        ar = dot2f(uh.h2[q], ur.h2[q], ar);
        az = dot2f(uh.h2[q], uz.h2[q], az);
        an = dot2f(uh.h2[q], un.h2[q], an);
      }
    }
    pbuf[0][s][j] = ar;
    pbuf[1][s][j] = az;
    pbuf[2][s][j] = an;
    __syncthreads();   // barrier 1: partials visible

    if (s == 0) {
      const float Ar = pbuf[0][0][j] + pbuf[0][1][j];
      const float Az = pbuf[1][0][j] + pbuf[1][1][j];
      const float An = pbuf[2][0][j] + pbuf[2][1][j];
      const float rv = fast_rcp(1.0f + __expf(-(igr + br + Ar)));
      const float zv = fast_rcp(1.0f + __expf(-(igz + bz + Az)));
      float npre = ign + bnb + rv * (An + bnj);
      npre = fminf(fmaxf(npre, -9.0f), 9.0f);
      const float e = __expf(-2.0f * npre);
      const float nv = (1.0f - e) * fast_rcp(1.0f + e);
      h = nv + zv * (h - nv);
      hbuf[j] = (_Float16)h;     // safe: all hbuf reads completed before barrier 1
      igr = (float)nr; igz = (float)nz; ign = (float)nn;
    }
    __syncthreads();   // barrier 2: new h visible
  }

  // --- epilogue: out[b] = h @ w_proj.T + b_proj  (fp32)
  if (s == 0) hf[j] = h;
  __syncthreads();
  if (tid < C_) {
    float acc = b_proj[tid];
    const float4v* wp = (const float4v*)(w_proj + (size_t)tid * H_);
#pragma unroll
    for (int p = 0; p < 64; ++p) {
      const float4v v = wp[p];
      acc += v[0] * hf[4 * p] + v[1] * hf[4 * p + 1] + v[2] * hf[4 * p + 2] + v[3] * hf[4 * p + 3];
    }
    out[bidx * C_ + tid] = acc;
  }
}

// ---------------------------------------------------------------------------
// Inputs (fp32): 0:x_seq[B,T,D] 1:w_ih[768,128] 2:w_hh[768,256] 3:b[768]
//                4:bn[256] 5:w_proj[128,256] 6:b_proj[128]
// Output: fp32 [B,C] = 8192 elems.
// Workspace: igates fp16 [B*T, 768] = 402,653,184 bytes.
// ---------------------------------------------------------------------------
extern "C" void kernel_launch(void* const* d_in, const int* in_sizes, int n_in,
                              void* d_out, int out_size, void* d_ws, size_t ws_size,
                              hipStream_t stream) {
  const float* x      = (const float*)d_in[0];
  const float* w_ih   = (const float*)d_in[1];
  const float* w_hh   = (const float*)d_in[2];
  const float* bias   = (const float*)d_in[3];
  const float* bn     = (const float*)d_in[4];
  const float* w_proj = (const float*)d_in[5];
  const float* b_proj = (const float*)d_in[6];
  float* out = (float*)d_out;
  _Float16* igs = (_Float16*)d_ws;   // needs 384 MiB

  igates_gemm<<<dim3((B_ * T_) / 256), dim3(256), 0, stream>>>(x, w_ih, igs);
  gru_scan<<<dim3(B_), dim3(512), 0, stream>>>(w_hh, bias, bn, w_proj, b_proj, igs, out);
}